// Round 4
// baseline (79.709 us; speedup 1.0000x reference)
//
#include <hip/hip_runtime.h>
#include <hip/hip_bf16.h>
#include <hip/hip_fp16.h>
#include <math.h>

// Problem constants: B=16, L=96, H=128.
#define BB 16
#define LL 96
#define HH 128

typedef __attribute__((ext_vector_type(8))) short short8;
typedef __attribute__((ext_vector_type(4))) float f32x4;

// ws byte offsets:
//  WS_W : frag-major bf16 W: frag id ((ig*4+kq)*6+ot), 64 lanes x 16B  -> 2,359,296 B
//  WS_E : dual-copy bf16 padded enc rows: [b][i][272 u32]              -> 1,671,168 B
//  WS_DEC / WS_CVG : fp32 dec_f / cvg_f
//  WS_P : fp16 partials [kc][b][w][o]                                  -> 6,291,456 B
#define WS_W_OFF   0
#define WS_E_OFF   2359296
#define WS_DEC_OFF 4030464
#define WS_CVG_OFF 4038656
#define WS_P_OFF   4044800

// ---------------- P: repack W (frag-major bf16), dual enc rows, dec_f, cvg_f ----------------
__global__ __launch_bounds__(256) void prep_kernel(
        const float* __restrict__ hidden,
        const float* __restrict__ enc,
        const float* __restrict__ coverage,
        const float* __restrict__ attn_w,
        const float* __restrict__ cvg_w,
        const float* __restrict__ cvg_b,
        const float* __restrict__ dec_w,
        const float* __restrict__ dec_b,
        char* __restrict__ wsb) {
    const int bid = blockIdx.x;
    const int tid = threadIdx.x;
    if (bid < 96) {
        // W slice kh=63, frag-major repack to bf16.
        const int ig = bid;
        unsigned short* wout = (unsigned short*)(wsb + WS_W_OFF);
        for (int base = tid * 8; base < LL * HH; base += 256 * 8) {
            const int o = base >> 7, k = base & 127;
            const int kq = k >> 5, h2 = (k >> 3) & 3;
            const int ot = o >> 4, l2 = o & 15;
            const float* src = attn_w + ((size_t)(o * LL + ig) * 16384 + 8064 + k);
            union { unsigned short us[8]; uint4 u4; } tm;
#pragma unroll
            for (int j = 0; j < 8; ++j) {
                __hip_bfloat16 h = __float2bfloat16(src[j]);
                tm.us[j] = *(unsigned short*)&h;
            }
            uint4* dst = (uint4*)(wout + ((size_t)((ig * 4 + kq) * 6 + ot) * 512
                                          + (h2 * 16 + l2) * 8));
            *dst = tm.u4;
        }
    } else if (bid < 112) {
        // dual-copy bf16 padded enc rows: per row 272 u32:
        //  [0..127]  w0[i] = (e(2i),   e(2i+1))
        //  [129..256] w1[i] = (e(2i+1), e(2i+2));  e(t)=enc[t-63] for t in [63,191) else 0
        const int b = bid - 96;
        unsigned int* eout = (unsigned int*)(wsb + WS_E_OFF) + (size_t)b * LL * 272;
        const float* esrc = enc + (size_t)b * LL * HH;
        for (int i = 0; i < LL; ++i) {
            for (int c = tid; c < 272; c += 256) {
                int t0 = -1, t1 = -1;
                if (c < 128) { t0 = 2 * c; t1 = 2 * c + 1; }
                else if (c >= 129 && c < 257) { int i2 = c - 129; t0 = 2 * i2 + 1; t1 = 2 * i2 + 2; }
                unsigned int lo16 = 0, hi16 = 0;
                if (t0 >= 63 && t0 < 191) {
                    __hip_bfloat16 h = __float2bfloat16(esrc[i * HH + t0 - 63]);
                    lo16 = *(unsigned short*)&h;
                }
                if (t1 >= 63 && t1 < 191) {
                    __hip_bfloat16 h = __float2bfloat16(esrc[i * HH + t1 - 63]);
                    hi16 = *(unsigned short*)&h;
                }
                eout[i * 272 + c] = lo16 | (hi16 << 16);
            }
        }
    } else {
        const int b = bid - 112;
        float* decf = (float*)(wsb + WS_DEC_OFF);
        float* cvgf = (float*)(wsb + WS_CVG_OFF);
        __shared__ float hid[HH];
        __shared__ float cov[LL];
        if (tid < HH) hid[tid] = hidden[b * HH + tid];
        if (tid < LL) cov[tid] = coverage[b * LL + tid];
        __syncthreads();
        if (tid < HH) {
            float acc = dec_b[tid];
            for (int k = 0; k < HH; ++k) acc += hid[k] * dec_w[tid * HH + k];
            decf[b * HH + tid] = acc;
        } else if (tid < HH + LL) {
            const int t = tid - HH;
            float a2 = cvg_b[t];
            for (int i2 = 0; i2 < LL; ++i2)
                a2 += cov[i2] * cvg_w[((size_t)t * LL + i2) * HH + 63];
            cvgf[b * LL + t] = a2;
        }
    }
}

// ---------------- M: bf16 MFMA, 8 waves = 4 k-quarters x 2 w-halves ----------------
// grid (kc=16, b=16) x 512 threads. Per block: 6 i-rows, K=768.
// A-frags direct from global (frag-major), B-frags from dual-copy LDS row.
__global__ __launch_bounds__(512, 2) void mfma_kernel(char* __restrict__ wsb) {
    const int kc = blockIdx.x;
    const int b  = blockIdx.y;
    const int tid    = threadIdx.x;
    const int lane   = tid & 63;
    const int waveid = tid >> 6;
    const int lo = lane & 15;
    const int hi = lane >> 4;
    const int kq    = waveid >> 1;   // k-quarter 0..3
    const int whalf = waveid & 1;    // w-half 0..1

    __shared__ unsigned int rowbuf[2][272];
    __shared__ float red[6][1024];   // 24KB cross-wave reduce scratch

    const unsigned short* Wp = (const unsigned short*)(wsb + WS_W_OFF);
    const unsigned int* Ep = (const unsigned int*)(wsb + WS_E_OFF)
                             + ((size_t)b * LL + kc * 6) * 272;
    __half* Pp = (__half*)(wsb + WS_P_OFF);

    f32x4 acc[6][4];
#pragma unroll
    for (int ot = 0; ot < 6; ++ot)
#pragma unroll
        for (int wt = 0; wt < 4; ++wt) acc[ot][wt] = f32x4{0.f, 0.f, 0.f, 0.f};

    short8 afA[6], afB[6];
    uint4 sreg;

    auto stageIssue = [&](int r) {
        if (tid < 68) sreg = *(const uint4*)(Ep + r * 272 + tid * 4);
    };
    auto stageWrite = [&](int bufi) {
        if (tid < 68) *(uint4*)&rowbuf[bufi][tid * 4] = sreg;
    };
    auto loadA = [&](int r, short8* af) {
        const unsigned short* base =
            Wp + (size_t)(((kc * 6 + r) * 4 + kq) * 6) * 512 + lane * 8;
#pragma unroll
        for (int ot = 0; ot < 6; ++ot)
            af[ot] = *(const short8*)(base + ot * 512);
    };
    auto compute = [&](int bufi, short8* af) {
        const unsigned int* row = rowbuf[bufi];
#pragma unroll
        for (int wt = 0; wt < 4; ++wt) {
            const int t0 = kq * 32 + whalf * 64 + wt * 16 + hi * 8 + lo;
            const unsigned int* arr = row + ((lo & 1) ? 129 : 0) + (t0 >> 1);
            union { uint4 u; short8 s; } bf;
            bf.u.x = arr[0]; bf.u.y = arr[1]; bf.u.z = arr[2]; bf.u.w = arr[3];
#pragma unroll
            for (int ot = 0; ot < 6; ++ot)
                acc[ot][wt] = __builtin_amdgcn_mfma_f32_16x16x32_bf16(
                    af[ot], bf.s, acc[ot][wt], 0, 0, 0);
        }
    };

    // prologue: row 0
    stageIssue(0); loadA(0, afA); stageWrite(0);
    __syncthreads();
    // r=0
    stageIssue(1); loadA(1, afB); compute(0, afA); stageWrite(1);
    __syncthreads();
    // r=1
    stageIssue(2); loadA(2, afA); compute(1, afB); stageWrite(0);
    __syncthreads();
    // r=2
    stageIssue(3); loadA(3, afB); compute(0, afA); stageWrite(1);
    __syncthreads();
    // r=3
    stageIssue(4); loadA(4, afA); compute(1, afB); stageWrite(0);
    __syncthreads();
    // r=4
    stageIssue(5); loadA(5, afB); compute(0, afA); stageWrite(1);
    __syncthreads();
    // r=5
    compute(1, afB);

    // cross-wave kq-reduce (6 rounds of 24KB scratch) + fp16 partial store
#pragma unroll
    for (int ot = 0; ot < 6; ++ot) {
        __syncthreads();
        if (waveid >= 2) {
            const int slot = waveid - 2;
#pragma unroll
            for (int wt = 0; wt < 4; ++wt)
                *(f32x4*)&red[slot][(wt * 64 + lane) * 4] = acc[ot][wt];
        }
        __syncthreads();
        if (waveid < 2) {
#pragma unroll
            for (int s = 0; s < 3; ++s)
#pragma unroll
                for (int wt = 0; wt < 4; ++wt)
                    acc[ot][wt] += *(const f32x4*)&red[s * 2 + whalf][(wt * 64 + lane) * 4];
#pragma unroll
            for (int wt = 0; wt < 4; ++wt) {
                const int w  = whalf * 64 + wt * 16 + lo;
                const int o0 = ot * 16 + hi * 4;
                __half2 p01 = __floats2half2_rn(acc[ot][wt][0], acc[ot][wt][1]);
                __half2 p23 = __floats2half2_rn(acc[ot][wt][2], acc[ot][wt][3]);
                __half2* dst = (__half2*)(Pp + (((size_t)(kc * BB + b) * HH + w) * LL + o0));
                dst[0] = p01; dst[1] = p23;
            }
        }
    }
}

// ---------------- RF: sum partials + tanh·v -> scores -> softmax -> outputs ----------------
__global__ __launch_bounds__(256) void reduceF_kernel(
        const float* __restrict__ attn_b,
        const float* __restrict__ vvec,
        const float* __restrict__ coverage,
        const float* __restrict__ enc,
        const char* __restrict__ wsb,
        float* __restrict__ out) {
    const int b = blockIdx.x;
    const int t = threadIdx.x;
    const int w = t >> 1, oh = t & 1;
    const __half* Pp = (const __half*)(wsb + WS_P_OFF);
    const float* dec = (const float*)(wsb + WS_DEC_OFF);
    const float* cvg = (const float*)(wsb + WS_CVG_OFF);

    __shared__ float sA[LL], sC[LL];
    __shared__ float scr[LL][130];
    __shared__ float sc[LL], at[LL];

    if (t < LL) { sA[t] = attn_b[t]; sC[t] = cvg[b * LL + t]; }
    __syncthreads();

    float sum[48];
#pragma unroll
    for (int j = 0; j < 48; ++j) sum[j] = 0.f;
    for (int kc = 0; kc < 16; ++kc) {
        const __half2* p2 = (const __half2*)(Pp + (((size_t)(kc * BB + b) * HH + w) * LL + oh * 48));
#pragma unroll
        for (int q = 0; q < 24; ++q) {
            __half2 h = p2[q];
            sum[2 * q]     += __low2float(h);
            sum[2 * q + 1] += __high2float(h);
        }
    }
    const float dv = dec[b * HH + w];
    const float vv = vvec[b * HH + w];
#pragma unroll
    for (int j = 0; j < 48; ++j) {
        const int o = oh * 48 + j;
        scr[o][w] = tanhf(sum[j] + sA[o] + sC[o] + dv) * vv;
    }
    __syncthreads();
    if (t < LL) {
        float s = 0.f;
        for (int ww = 0; ww < HH; ++ww) s += scr[t][ww];
        sc[t] = s;
    }
    __syncthreads();
    float mx = -1e30f;
    for (int l = 0; l < LL; ++l) mx = fmaxf(mx, sc[l]);
    float den = 0.f;
    for (int l = 0; l < LL; ++l) den += expf(sc[l] - mx);
    if (t < LL) {
        float a = expf(sc[t] - mx) / den;
        at[t] = a;
        out[BB * HH + b * LL + t] = a;
        out[BB * HH + BB * LL + b * LL + t] = coverage[b * LL + t] + a;
    }
    __syncthreads();
    if (t < HH) {
        float c = 0.f;
        for (int l = 0; l < LL; ++l) c += at[l] * enc[((size_t)b * LL + l) * HH + t];
        out[b * HH + t] = c;
    }
}

extern "C" void kernel_launch(void* const* d_in, const int* in_sizes, int n_in,
                              void* d_out, int out_size, void* d_ws, size_t ws_size,
                              hipStream_t stream) {
    const float* hidden   = (const float*)d_in[0];
    const float* enc      = (const float*)d_in[1];
    const float* coverage = (const float*)d_in[2];
    const float* attn_w   = (const float*)d_in[3];
    const float* attn_b   = (const float*)d_in[4];
    const float* cvg_w    = (const float*)d_in[5];
    const float* cvg_b    = (const float*)d_in[6];
    const float* dec_w    = (const float*)d_in[7];
    const float* dec_b    = (const float*)d_in[8];
    const float* vvec     = (const float*)d_in[9];
    float* out = (float*)d_out;
    char* wsb = (char*)d_ws;

    prep_kernel<<<128, 256, 0, stream>>>(hidden, enc, coverage, attn_w,
                                         cvg_w, cvg_b, dec_w, dec_b, wsb);
    mfma_kernel<<<dim3(16, BB), 512, 0, stream>>>(wsb);
    reduceF_kernel<<<BB, 256, 0, stream>>>(attn_b, vvec, coverage, enc, wsb, out);
}